// Round 4
// baseline (80.204 us; speedup 1.0000x reference)
//
#include <hip/hip_runtime.h>
#include <math.h>
#include <stdint.h>

#define RR 1000
#define CC 1024
#define NCLS 81
#define HH 1024.0f
#define MIN_CONF_V 0.05f
#define NMS_THR_V 0.5f
#define NEGV -1e9f

// ---------------- Kernel 0: repack weights -> wP[12][256][32] ----------------
// wP[g][kstep][ci*4 + kk] = w[:, g*8+ci] at k = kstep*4+kk   (96 padded cols)
__global__ __launch_bounds__(128) void k0_wt(
    const float* __restrict__ w_cls, const float* __restrict__ w_delta,
    float* __restrict__ wP)
{
    const int t = threadIdx.x;
    if (t >= 96) return;
    const int c = t;
    const int g = c >> 3, ci = c & 7;
    #pragma unroll
    for (int kk = 0; kk < 4; ++kk) {
        const int k = blockIdx.x * 4 + kk;
        float v = 0.f;
        if (c < NCLS)            v = w_cls[(size_t)k * NCLS + c];
        else if (c < NCLS + 4)   v = w_delta[(size_t)k * 4 + (c - NCLS)];
        wP[(size_t)g * 8192 + (size_t)(k >> 2) * 32 + ci * 4 + (k & 3)] = v;
    }
}

// ---------------- Kernel 1: split-K f32 GEMM, w via uniform (scalar) loads ----------------
// grid 250 = 125 row-tiles x 2 K-halves. 768 thr = 12 waves.
// wave wq: 64 rows (lane=row) x 8 cols (g=wq). x in LDS (XOR swizzle), w direct from wP.
__global__ __launch_bounds__(768) void k1_gemm(
    const float* __restrict__ x, const float* __restrict__ wP,
    float* __restrict__ partial)
{
    __shared__ float4 xs4[2][1024];           // [buf][row*16 + swz f4], 32 KB

    const int t = threadIdx.x;
    const int bx = blockIdx.x;
    const int rt = bx >> 1;                   // 0..124
    const int kh = bx & 1;                    // K half
    const int row0 = rt * 64;
    const int kbase = kh * 512;
    const int lane = t & 63;                  // = row within tile
    const int swz = lane & 15;
    const int wq = __builtin_amdgcn_readfirstlane(t >> 6);  // 0..11, wave-uniform

    // staging: 1024 float4 per chunk; thread t does slot t, and slot 768+t if t<256
    const int r_s0 = t >> 4;                  // 0..47
    const int f_s0 = t & 15;
    const int dst0 = (r_s0 << 4) + (f_s0 ^ (r_s0 & 15));
    const size_t gsrc0 = (size_t)(row0 + r_s0) * CC + kbase + f_s0 * 4;
    const int r_s1 = 48 + (t >> 4);           // rows 48..63 (only t<256)
    const int dst1 = (r_s1 << 4) + ((t & 15) ^ (r_s1 & 15));
    const size_t gsrc1 = (size_t)(row0 + r_s1) * CC + kbase + (t & 15) * 4;

    float acc[8] = {0.f, 0.f, 0.f, 0.f, 0.f, 0.f, 0.f, 0.f};

    float4 pv0 = *(const float4*)(x + gsrc0);
    float4 pv1 = make_float4(0.f, 0.f, 0.f, 0.f);
    if (t < 256) pv1 = *(const float4*)(x + gsrc1);

    const int xbase = lane << 4;
    int cur = 0;
    for (int ch = 0; ch < 8; ++ch) {
        xs4[cur][dst0] = pv0;
        if (t < 256) xs4[cur][dst1] = pv1;
        __syncthreads();
        if (ch < 7) {                         // issue next-chunk loads under compute
            const size_t off = (size_t)(ch + 1) * 64;
            pv0 = *(const float4*)(x + gsrc0 + off);
            if (t < 256) pv1 = *(const float4*)(x + gsrc1 + off);
        }
        // wave-uniform w base for this chunk: 16 steps x 32 floats, static offsets
        const float* __restrict__ wb = wP + ((size_t)wq << 13)
                                     + (size_t)(kh * 128 + ch * 16) * 32;
        const float4* xsb = xs4[cur];
        #pragma unroll
        for (int s = 0; s < 16; ++s) {
            const float4 xv = xsb[xbase + (s ^ swz)];
            #pragma unroll
            for (int j = 0; j < 8; ++j) {
                acc[j] = fmaf(xv.x, wb[s * 32 + j * 4 + 0], acc[j]);
                acc[j] = fmaf(xv.y, wb[s * 32 + j * 4 + 1], acc[j]);
                acc[j] = fmaf(xv.z, wb[s * 32 + j * 4 + 2], acc[j]);
                acc[j] = fmaf(xv.w, wb[s * 32 + j * 4 + 3], acc[j]);
            }
        }
        __syncthreads();
        cur ^= 1;
    }

    float* po = partial + ((size_t)(kh * 8000 + row0 + lane)) * 96 + wq * 8;
    *(float4*)(po + 0) = make_float4(acc[0], acc[1], acc[2], acc[3]);
    *(float4*)(po + 4) = make_float4(acc[4], acc[5], acc[6], acc[7]);
}

// ---------------- Kernel 1b: reduce halves + softmax/argmax + bbox ----------------
__global__ __launch_bounds__(1024) void k1b_epi(
    const float* __restrict__ partial, const float* __restrict__ b_cls,
    const float* __restrict__ b_delta, const float* __restrict__ rois,
    float* __restrict__ bx_ws, float* __restrict__ sc_ws, float* __restrict__ cid_ws)
{
    const int t = threadIdx.x;
    const int rb = t >> 4;
    const int e = t & 15;
    const int gr = blockIdx.x * 64 + rb;
    const float* pa = partial + (size_t)gr * 96;
    const float* pb = partial + (size_t)(8000 + gr) * 96;

    float v[6];
    float vmax = -INFINITY;
    int imax = 1 << 20;
    #pragma unroll
    for (int s = 0; s < 6; ++s) {
        const int c = e + 16 * s;
        if (c < NCLS) {
            const float val = pa[c] + pb[c] + b_cls[c];
            v[s] = val;
            if (val > vmax) { vmax = val; imax = c; }
        } else v[s] = -INFINITY;
    }
    #pragma unroll
    for (int m = 8; m >= 1; m >>= 1) {
        const float v2 = __shfl_xor(vmax, m);
        const int   i2 = __shfl_xor(imax, m);
        if (v2 > vmax || (v2 == vmax && i2 < imax)) { vmax = v2; imax = i2; }
    }
    float sume = 0.f;
    #pragma unroll
    for (int s = 0; s < 6; ++s) {
        const int c = e + 16 * s;
        if (c < NCLS) sume += expf(v[s] - vmax);
    }
    #pragma unroll
    for (int m = 8; m >= 1; m >>= 1) sume += __shfl_xor(sume, m);

    if (e == 0) {
        const float score = 1.0f / sume;
        const int cid = imax;
        const float d0 = (pa[81] + pb[81] + b_delta[0]) * 0.1f;
        const float d1 = (pa[82] + pb[82] + b_delta[1]) * 0.1f;
        const float d2 = (pa[83] + pb[83] + b_delta[2]) * 0.2f;
        const float d3 = (pa[84] + pb[84] + b_delta[3]) * 0.2f;
        const float y1 = rois[(size_t)gr * 5 + 1] * HH;
        const float x1 = rois[(size_t)gr * 5 + 2] * HH;
        const float y2 = rois[(size_t)gr * 5 + 3] * HH;
        const float x2 = rois[(size_t)gr * 5 + 4] * HH;
        const float h = y2 - y1, w = x2 - x1;
        const float cy = y1 + 0.5f * h + d0 * h;
        const float cx = x1 + 0.5f * w + d1 * w;
        const float h2 = h * expf(d2);
        const float w2 = w * expf(d3);
        const float by1 = fminf(fmaxf(cy - 0.5f * h2, 0.f), HH);
        const float bx1 = fminf(fmaxf(cx - 0.5f * w2, 0.f), HH);
        const float by2 = fminf(fmaxf(cy + 0.5f * h2, 0.f), HH);
        const float bx2 = fminf(fmaxf(cx + 0.5f * w2, 0.f), HH);
        const bool valid = (cid > 0) && (score >= MIN_CONF_V);
        bx_ws[(size_t)gr * 4 + 0] = by1;
        bx_ws[(size_t)gr * 4 + 1] = bx1;
        bx_ws[(size_t)gr * 4 + 2] = by2;
        bx_ws[(size_t)gr * 4 + 3] = bx2;
        sc_ws[gr]  = valid ? score : NEGV;
        cid_ws[gr] = (float)cid;
    }
}

// ---------------- Kernel 2: per-batch stable sort + greedy NMS + emit ----------------
__global__ __launch_bounds__(1024) void k2_nms(
    const float* __restrict__ bx_ws, const float* __restrict__ sc_ws,
    const float* __restrict__ cid_ws, float* __restrict__ det)
{
    __shared__ unsigned long long keys[1024];
    __shared__ float sy1[1024], sx1[1024], sy2[1024], sx2[1024];
    __shared__ float scl[1024], ssc[1024];
    __shared__ unsigned char supp[1024];
    __shared__ int s_cnt;

    const int b = blockIdx.x;
    const int t = threadIdx.x;
    const int base = b * RR;

    unsigned long long key = 0ull;
    if (t < RR) {
        const float s = sc_ws[base + t];
        unsigned int u = __float_as_uint(s);
        u = (u & 0x80000000u) ? ~u : (u | 0x80000000u);
        key = ((unsigned long long)u << 32) | (unsigned int)(~(unsigned int)t);
    }
    keys[t] = key;
    __syncthreads();

    for (int k = 2; k <= 1024; k <<= 1) {
        for (int j = k >> 1; j > 0; j >>= 1) {
            const int ixj = t ^ j;
            if (ixj > t) {
                const unsigned long long a = keys[t];
                const unsigned long long c = keys[ixj];
                const bool desc = ((t & k) == 0);
                if (desc ? (a < c) : (a > c)) { keys[t] = c; keys[ixj] = a; }
            }
            __syncthreads();
        }
    }

    const unsigned int lo = (unsigned int)keys[t];
    const int orig = (int)(~lo);
    float sv = NEGV;
    if (orig >= 0 && orig < RR) {
        const int g = base + orig;
        sy1[t] = bx_ws[(size_t)g * 4 + 0];
        sx1[t] = bx_ws[(size_t)g * 4 + 1];
        sy2[t] = bx_ws[(size_t)g * 4 + 2];
        sx2[t] = bx_ws[(size_t)g * 4 + 3];
        scl[t] = cid_ws[g];
        sv = sc_ws[g];
    } else {
        sy1[t] = sx1[t] = sy2[t] = sx2[t] = 0.f;
        scl[t] = -1.f;
    }
    ssc[t] = sv;
    supp[t] = 0;
    if (t == 0) s_cnt = 0;
    const int V = __syncthreads_count(sv > (NEGV * 0.5f));

    for (int i = 0; i < V; ++i) {
        __syncthreads();
        if (s_cnt >= 100) break;
        if (!supp[i]) {
            if (t > i && t < V && scl[t] == scl[i]) {
                const float yy1 = fmaxf(sy1[i], sy1[t]);
                const float xx1 = fmaxf(sx1[i], sx1[t]);
                const float yy2 = fminf(sy2[i], sy2[t]);
                const float xx2 = fminf(sx2[i], sx2[t]);
                const float inter = fmaxf(yy2 - yy1, 0.f) * fmaxf(xx2 - xx1, 0.f);
                const float ai = (sy2[i] - sy1[i]) * (sx2[i] - sx1[i]);
                const float at = (sy2[t] - sy1[t]) * (sx2[t] - sx1[t]);
                const float uni = ai + at - inter;
                if (inter / fmaxf(uni, 1e-8f) > NMS_THR_V) supp[t] = 1;
            }
            if (t == 0) {
                const int slot = s_cnt;
                if (slot < 100) {
                    float* o = det + ((size_t)b * 100 + slot) * 6;
                    o[0] = sy1[i]; o[1] = sx1[i]; o[2] = sy2[i]; o[3] = sx2[i];
                    o[4] = scl[i]; o[5] = ssc[i];
                }
                s_cnt = slot + 1;
            }
        }
    }
    __syncthreads();
    int cnt = s_cnt;
    if (cnt > 100) cnt = 100;
    for (int idx = t; idx < 600; idx += 1024) {
        if (idx >= cnt * 6) det[(size_t)b * 600 + idx] = 0.f;
    }
}

extern "C" void kernel_launch(void* const* d_in, const int* in_sizes, int n_in,
                              void* d_out, int out_size, void* d_ws, size_t ws_size,
                              hipStream_t stream) {
    const float* x       = (const float*)d_in[0];
    const float* w_cls   = (const float*)d_in[1];
    const float* b_cls   = (const float*)d_in[2];
    const float* w_delta = (const float*)d_in[3];
    const float* b_delta = (const float*)d_in[4];
    const float* rois    = (const float*)d_in[5];
    float* out = (float*)d_out;

    float* bx_ws   = (float*)d_ws;               // [8000][4]
    float* sc_ws   = bx_ws + 8000 * 4;           // [8000]
    float* cid_ws  = sc_ws + 8000;               // [8000]
    float* wP      = cid_ws + 8000;              // [12][256][32] = 98304
    float* partial = wP + 98304;                 // [2][8000][96] = 1536000

    k0_wt<<<256, 128, 0, stream>>>(w_cls, w_delta, wP);
    k1_gemm<<<250, 768, 0, stream>>>(x, wP, partial);
    k1b_epi<<<125, 1024, 0, stream>>>(partial, b_cls, b_delta, rois,
                                      bx_ws, sc_ws, cid_ws);
    k2_nms<<<8, 1024, 0, stream>>>(bx_ws, sc_ws, cid_ws, out);
}

// Round 5
// 32.993 us; speedup vs baseline: 2.4309x; 2.4309x over previous
//
#include <hip/hip_runtime.h>
#include <math.h>
#include <stdint.h>

#define RR 1000
#define CC 1024
#define NCLS 81
#define HH 1024.0f
#define MIN_CONF_V 0.05f
#define NMS_THR_V 0.5f
#define NEGV -1e9f

typedef __attribute__((ext_vector_type(8))) short bf16x8;
typedef __attribute__((ext_vector_type(4))) float f32x4;

__device__ __forceinline__ unsigned short f2bf(float f) {
    unsigned int u = __float_as_uint(f);
    return (unsigned short)((u + 0x7FFFu + ((u >> 16) & 1u)) >> 16);
}
__device__ __forceinline__ float bf2f(unsigned short h) {
    return __uint_as_float(((unsigned int)h) << 16);
}

// ---------------- Kernel 0: pack w -> B-fragment order, bf16 hi/lo ----------------
// B-frag for mfma_f32_16x16x32_bf16: lane l supplies B[k][col], col=l&15, k=(l>>4)*8+j.
// wh/wl layout: ((ct*32 + sg)*64 + l)*8 + j   (ushort), ct=col-tile 0..5, sg=k-step 0..31
__global__ __launch_bounds__(64) void k0_pack(
    const float* __restrict__ w_cls, const float* __restrict__ w_delta,
    unsigned short* __restrict__ wh, unsigned short* __restrict__ wl)
{
    const int ct = blockIdx.x >> 5;
    const int sg = blockIdx.x & 31;
    const int l = threadIdx.x;
    const int col = ct * 16 + (l & 15);
    const int kbase = sg * 32 + (l >> 4) * 8;
    unsigned short h[8], lo[8];
    #pragma unroll
    for (int j = 0; j < 8; ++j) {
        const int k = kbase + j;
        float v = 0.f;
        if (col < NCLS)          v = w_cls[(size_t)k * NCLS + col];
        else if (col < NCLS + 4) v = w_delta[(size_t)k * 4 + (col - NCLS)];
        h[j] = f2bf(v);
        lo[j] = f2bf(v - bf2f(h[j]));
    }
    const size_t base = ((size_t)(ct * 32 + sg) * 64 + l) * 8;
    uint4 uh, ul;
    uh.x = (unsigned)h[0] | ((unsigned)h[1] << 16);
    uh.y = (unsigned)h[2] | ((unsigned)h[3] << 16);
    uh.z = (unsigned)h[4] | ((unsigned)h[5] << 16);
    uh.w = (unsigned)h[6] | ((unsigned)h[7] << 16);
    ul.x = (unsigned)lo[0] | ((unsigned)lo[1] << 16);
    ul.y = (unsigned)lo[2] | ((unsigned)lo[3] << 16);
    ul.z = (unsigned)lo[4] | ((unsigned)lo[5] << 16);
    ul.w = (unsigned)lo[6] | ((unsigned)lo[7] << 16);
    *(uint4*)&wh[base] = uh;
    *(uint4*)&wl[base] = ul;
}

// ---------------- Kernel 1: MFMA GEMM (split-bf16 x3) + fused epilogue ----------------
// 500 blocks x 384 thr (6 waves). Block: 16 rows x 96 cols, full K=1024.
// Wave w = col-tile ct. A (x) hi/lo staged in LDS per 64-k chunk; B prefetched from wh/wl.
__global__ __launch_bounds__(384) void k1_head(
    const float* __restrict__ x,
    const unsigned short* __restrict__ wh, const unsigned short* __restrict__ wl,
    const float* __restrict__ b_cls, const float* __restrict__ b_delta,
    const float* __restrict__ rois,
    float* __restrict__ bx_ws, float* __restrict__ sc_ws, float* __restrict__ cid_ws)
{
    __shared__ __align__(16) unsigned short xh[2][16][64];
    __shared__ __align__(16) unsigned short xl[2][16][64];
    __shared__ float outb[16 * 104];

    const int t = threadIdx.x;
    const int lane = t & 63;
    const int ct = t >> 6;                    // wave = col-tile 0..5
    const int row0 = blockIdx.x * 16;

    // x staging (first 256 threads): row = t>>4, f4-slot = t&15
    const int srow = t >> 4;
    const int sk4 = (t & 15) * 4;
    const size_t xsrc = (size_t)(row0 + srow) * CC + sk4;

    // A-frag LDS offset: row = lane&15, k = s*32 + (lane>>4)*8
    const int aoff0 = (lane & 15) * 64 + ((lane >> 4) << 3);         // s=0
    const int aoff1 = aoff0 + 32;                                    // s=1

    // B-frag base (ushort index): ((ct*32 + sg)*64 + lane)*8
    const unsigned short* whp = wh + ((size_t)(ct * 32) * 64 + lane) * 8;
    const unsigned short* wlp = wl + ((size_t)(ct * 32) * 64 + lane) * 8;
    const size_t bstep = 64 * 8;              // per k-step stride

    f32x4 acc = {0.f, 0.f, 0.f, 0.f};

    float4 xv = make_float4(0.f, 0.f, 0.f, 0.f);
    if (t < 256) xv = *(const float4*)(x + xsrc);

    bf16x8 B0h = *(const bf16x8*)(whp + 0 * bstep);
    bf16x8 B0l = *(const bf16x8*)(wlp + 0 * bstep);
    bf16x8 B1h = *(const bf16x8*)(whp + 1 * bstep);
    bf16x8 B1l = *(const bf16x8*)(wlp + 1 * bstep);

    int cur = 0;
    for (int c = 0; c < 16; ++c) {
        if (t < 256) {                        // convert + write chunk to LDS
            unsigned short h0 = f2bf(xv.x), h1 = f2bf(xv.y), h2 = f2bf(xv.z), h3 = f2bf(xv.w);
            ushort4 hv = make_ushort4(h0, h1, h2, h3);
            ushort4 lv = make_ushort4(f2bf(xv.x - bf2f(h0)), f2bf(xv.y - bf2f(h1)),
                                      f2bf(xv.z - bf2f(h2)), f2bf(xv.w - bf2f(h3)));
            *(ushort4*)&xh[cur][srow][sk4] = hv;
            *(ushort4*)&xl[cur][srow][sk4] = lv;
        }
        __syncthreads();

        bf16x8 N0h, N0l, N1h, N1l;
        if (c < 15) {                         // prefetch next chunk (x + B-frags)
            if (t < 256) xv = *(const float4*)(x + xsrc + (size_t)(c + 1) * 64);
            const size_t sg = (size_t)(2 * c + 2);
            N0h = *(const bf16x8*)(whp + sg * bstep);
            N0l = *(const bf16x8*)(wlp + sg * bstep);
            N1h = *(const bf16x8*)(whp + (sg + 1) * bstep);
            N1l = *(const bf16x8*)(wlp + (sg + 1) * bstep);
        }

        const bf16x8 a0h = *(const bf16x8*)&((const unsigned short*)xh[cur])[aoff0];
        const bf16x8 a0l = *(const bf16x8*)&((const unsigned short*)xl[cur])[aoff0];
        acc = __builtin_amdgcn_mfma_f32_16x16x32_bf16(a0h, B0h, acc, 0, 0, 0);
        acc = __builtin_amdgcn_mfma_f32_16x16x32_bf16(a0h, B0l, acc, 0, 0, 0);
        acc = __builtin_amdgcn_mfma_f32_16x16x32_bf16(a0l, B0h, acc, 0, 0, 0);
        const bf16x8 a1h = *(const bf16x8*)&((const unsigned short*)xh[cur])[aoff1];
        const bf16x8 a1l = *(const bf16x8*)&((const unsigned short*)xl[cur])[aoff1];
        acc = __builtin_amdgcn_mfma_f32_16x16x32_bf16(a1h, B1h, acc, 0, 0, 0);
        acc = __builtin_amdgcn_mfma_f32_16x16x32_bf16(a1h, B1l, acc, 0, 0, 0);
        acc = __builtin_amdgcn_mfma_f32_16x16x32_bf16(a1l, B1h, acc, 0, 0, 0);

        B0h = N0h; B0l = N0l; B1h = N1h; B1l = N1l;
        cur ^= 1;
        __syncthreads();
    }

    // C layout (m89-verified): col = lane&15, row = (lane>>4)*4 + r
    #pragma unroll
    for (int r = 0; r < 4; ++r)
        outb[((lane >> 4) * 4 + r) * 104 + ct * 16 + (lane & 15)] = acc[r];
    __syncthreads();

    if (t < 256) {
        const int row = t >> 4;
        const int e = t & 15;
        float vmax = -INFINITY;
        int imax = 1 << 20;
        float v[6];
        #pragma unroll
        for (int s = 0; s < 6; ++s) {
            const int cidx = e + 16 * s;
            if (cidx < NCLS) {
                const float val = outb[row * 104 + cidx] + b_cls[cidx];
                v[s] = val;
                if (val > vmax) { vmax = val; imax = cidx; }
            } else v[s] = -INFINITY;
        }
        #pragma unroll
        for (int m = 8; m >= 1; m >>= 1) {
            const float v2 = __shfl_xor(vmax, m);
            const int   i2 = __shfl_xor(imax, m);
            if (v2 > vmax || (v2 == vmax && i2 < imax)) { vmax = v2; imax = i2; }
        }
        float sume = 0.f;
        #pragma unroll
        for (int s = 0; s < 6; ++s) {
            const int cidx = e + 16 * s;
            if (cidx < NCLS) sume += expf(v[s] - vmax);
        }
        #pragma unroll
        for (int m = 8; m >= 1; m >>= 1) sume += __shfl_xor(sume, m);

        if (e == 0) {
            const int gr = row0 + row;
            const float score = 1.0f / sume;
            const int cid = imax;
            const float d0 = (outb[row * 104 + 81] + b_delta[0]) * 0.1f;
            const float d1 = (outb[row * 104 + 82] + b_delta[1]) * 0.1f;
            const float d2 = (outb[row * 104 + 83] + b_delta[2]) * 0.2f;
            const float d3 = (outb[row * 104 + 84] + b_delta[3]) * 0.2f;
            const float y1 = rois[(size_t)gr * 5 + 1] * HH;
            const float x1 = rois[(size_t)gr * 5 + 2] * HH;
            const float y2 = rois[(size_t)gr * 5 + 3] * HH;
            const float x2 = rois[(size_t)gr * 5 + 4] * HH;
            const float h = y2 - y1, w = x2 - x1;
            const float cy = y1 + 0.5f * h + d0 * h;
            const float cx = x1 + 0.5f * w + d1 * w;
            const float h2 = h * expf(d2);
            const float w2 = w * expf(d3);
            const float by1 = fminf(fmaxf(cy - 0.5f * h2, 0.f), HH);
            const float bx1 = fminf(fmaxf(cx - 0.5f * w2, 0.f), HH);
            const float by2 = fminf(fmaxf(cy + 0.5f * h2, 0.f), HH);
            const float bx2 = fminf(fmaxf(cx + 0.5f * w2, 0.f), HH);
            const bool valid = (cid > 0) && (score >= MIN_CONF_V);
            bx_ws[(size_t)gr * 4 + 0] = by1;
            bx_ws[(size_t)gr * 4 + 1] = bx1;
            bx_ws[(size_t)gr * 4 + 2] = by2;
            bx_ws[(size_t)gr * 4 + 3] = bx2;
            sc_ws[gr]  = valid ? score : NEGV;
            cid_ws[gr] = (float)cid;
        }
    }
}

// ---------------- Kernel 2: compact valid -> sort 256 -> greedy NMS -> emit ----------------
__global__ __launch_bounds__(256) void k2_nms(
    const float* __restrict__ bx_ws, const float* __restrict__ sc_ws,
    const float* __restrict__ cid_ws, float* __restrict__ det)
{
    __shared__ unsigned long long keys[256];
    __shared__ float sy1[256], sx1[256], sy2[256], sx2[256];
    __shared__ float scl[256], ssc[256];
    __shared__ unsigned char supp[256];
    __shared__ int s_cnt, s_num;

    const int b = blockIdx.x;
    const int t = threadIdx.x;
    const int base = b * RR;

    keys[t] = 0ull;
    if (t == 0) { s_cnt = 0; s_num = 0; }
    __syncthreads();

    // compact valid rows (order-independent; sort restores exact (score, idx) order)
    for (int r = t; r < RR; r += 256) {
        const float s = sc_ws[base + r];
        if (s > NEGV * 0.5f) {
            const int i = atomicAdd(&s_num, 1);
            if (i < 256) {
                unsigned int u = __float_as_uint(s) | 0x80000000u;   // s > 0 always
                keys[i] = ((unsigned long long)u << 32) | (unsigned int)(~(unsigned int)r);
            }
        }
    }
    __syncthreads();
    const int V = (s_num < 256) ? s_num : 256;

    // bitonic sort 256, descending (empty slots = 0 sort last)
    for (int k = 2; k <= 256; k <<= 1) {
        for (int j = k >> 1; j > 0; j >>= 1) {
            const int ixj = t ^ j;
            if (ixj > t) {
                const unsigned long long a = keys[t];
                const unsigned long long c = keys[ixj];
                const bool desc = ((t & k) == 0);
                if (desc ? (a < c) : (a > c)) { keys[t] = c; keys[ixj] = a; }
            }
            __syncthreads();
        }
    }

    if (t < V) {
        const int orig = (int)(~(unsigned int)keys[t]);
        const int g = base + orig;
        sy1[t] = bx_ws[(size_t)g * 4 + 0];
        sx1[t] = bx_ws[(size_t)g * 4 + 1];
        sy2[t] = bx_ws[(size_t)g * 4 + 2];
        sx2[t] = bx_ws[(size_t)g * 4 + 3];
        scl[t] = cid_ws[g];
        ssc[t] = sc_ws[g];
    } else {
        sy1[t] = sx1[t] = sy2[t] = sx2[t] = 0.f;
        scl[t] = -1.f;
        ssc[t] = NEGV;
    }
    supp[t] = 0;
    __syncthreads();

    for (int i = 0; i < V; ++i) {
        __syncthreads();
        if (s_cnt >= 100) break;
        if (!supp[i]) {
            if (t > i && t < V && scl[t] == scl[i]) {
                const float yy1 = fmaxf(sy1[i], sy1[t]);
                const float xx1 = fmaxf(sx1[i], sx1[t]);
                const float yy2 = fminf(sy2[i], sy2[t]);
                const float xx2 = fminf(sx2[i], sx2[t]);
                const float inter = fmaxf(yy2 - yy1, 0.f) * fmaxf(xx2 - xx1, 0.f);
                const float ai = (sy2[i] - sy1[i]) * (sx2[i] - sx1[i]);
                const float at = (sy2[t] - sy1[t]) * (sx2[t] - sx1[t]);
                const float uni = ai + at - inter;
                if (inter / fmaxf(uni, 1e-8f) > NMS_THR_V) supp[t] = 1;
            }
            if (t == 0) {
                const int slot = s_cnt;
                if (slot < 100) {
                    float* o = det + ((size_t)b * 100 + slot) * 6;
                    o[0] = sy1[i]; o[1] = sx1[i]; o[2] = sy2[i]; o[3] = sx2[i];
                    o[4] = scl[i]; o[5] = ssc[i];
                }
                s_cnt = slot + 1;
            }
        }
    }
    __syncthreads();
    int cnt = s_cnt;
    if (cnt > 100) cnt = 100;
    for (int idx = t; idx < 600; idx += 256) {
        if (idx >= cnt * 6) det[(size_t)b * 600 + idx] = 0.f;
    }
}

extern "C" void kernel_launch(void* const* d_in, const int* in_sizes, int n_in,
                              void* d_out, int out_size, void* d_ws, size_t ws_size,
                              hipStream_t stream) {
    const float* x       = (const float*)d_in[0];
    const float* w_cls   = (const float*)d_in[1];
    const float* b_cls   = (const float*)d_in[2];
    const float* w_delta = (const float*)d_in[3];
    const float* b_delta = (const float*)d_in[4];
    const float* rois    = (const float*)d_in[5];
    float* out = (float*)d_out;

    float* bx_ws   = (float*)d_ws;               // [8000][4]
    float* sc_ws   = bx_ws + 8000 * 4;           // [8000]
    float* cid_ws  = sc_ws + 8000;               // [8000]
    unsigned short* wh = (unsigned short*)(cid_ws + 8000);   // 6*32*64*8 = 98304 ushort
    unsigned short* wl = wh + 98304;

    k0_pack<<<192, 64, 0, stream>>>(w_cls, w_delta, wh, wl);
    k1_head<<<500, 384, 0, stream>>>(x, wh, wl, b_cls, b_delta, rois,
                                     bx_ws, sc_ws, cid_ws);
    k2_nms<<<8, 256, 0, stream>>>(bx_ws, sc_ws, cid_ws, out);
}